// Round 1
// baseline (6585.072 us; speedup 1.0000x reference)
//
#include <hip/hip_runtime.h>
#include <hip/hip_bf16.h>
#include <math.h>

#define BB 32
#define TT 20
#define VV 30000

__device__ __forceinline__ float dot4(float4 a, float4 b) {
  return a.x*b.x + a.y*b.y + a.z*b.z + a.w*b.w;
}

// ---------------- prep: attr_cat gather + teacher-forced input embeddings ----------------
__global__ __launch_bounds__(256) void k_prep(const int* __restrict__ user, const int* __restrict__ product,
    const int* __restrict__ rating, const int* __restrict__ trg,
    const float* __restrict__ embed, const float* __restrict__ user_w,
    const float* __restrict__ product_w, const float* __restrict__ rating_w,
    float* __restrict__ attr_cat, float* __restrict__ xs)
{
  int i = blockIdx.x*256 + threadIdx.x;
  if (i < BB*1536) {
    int b = i / 1536, j = i - b*1536;
    float v;
    if (j < 512)       v = user_w[(size_t)user[b]*512 + j];
    else if (j < 1024) v = product_w[(size_t)product[b]*512 + (j-512)];
    else               v = rating_w[(size_t)rating[b]*512 + (j-1024)];
    attr_cat[i] = v;
  }
  int i2 = i - BB*1536;
  if (i2 >= 0 && i2 < TT*BB*512) {
    int t = i2 >> 14;          // / (32*512)
    int r = i2 & 16383;
    int b = r >> 9, e = r & 511;
    int tok = (t == 0) ? 1 : trg[b*TT + (t-1)];   // bos = embed[1], teacher forcing shift
    xs[i2] = embed[(size_t)tok*512 + e];
  }
}

// ---------------- encoder: attr_final = leaky_relu(attr_cat @ enc_w.T + enc_b) ----------------
// h0_init = cols [0,512), h1_init = ctx_init = cols [512,1024)
__global__ __launch_bounds__(256) void k_enc(const float* __restrict__ attr_cat, const float* __restrict__ enc_w,
    const float* __restrict__ enc_b, float* __restrict__ h0, float* __restrict__ h1, float* __restrict__ ctx0)
{
  int i = blockIdx.x*256 + threadIdx.x;   // 32768
  int b = i & 31, j = i >> 5;             // j in [0,1024)
  const float4* a = (const float4*)(attr_cat + b*1536);
  const float4* w = (const float4*)(enc_w + (size_t)j*1536);
  float acc = 0.f;
  #pragma unroll 8
  for (int k = 0; k < 384; k++) acc += dot4(a[k], w[k]);
  acc += enc_b[j];
  float v = acc > 0.f ? acc : 0.01f*acc;   // leaky_relu slope 0.01
  if (j < 512) h0[b*512 + j] = v;
  else { h1[b*512 + (j-512)] = v; ctx0[b*512 + (j-512)] = v; }
}

// ---------------- proj_key = encoder_attr @ key_w.T  [B,3,H] ----------------
__global__ __launch_bounds__(256) void k_key(const float* __restrict__ attr_cat, const float* __restrict__ key_w,
    float* __restrict__ proj_key)
{
  int i = blockIdx.x*256 + threadIdx.x;   // 49152
  int b = i & 31, j = i >> 5;             // j in [0,1536)
  int k3 = j >> 9, h = j & 511;
  const float4* a = (const float4*)(attr_cat + b*1536 + k3*512);
  const float4* w = (const float4*)(key_w + (size_t)h*512);
  float acc = 0.f;
  #pragma unroll 8
  for (int k = 0; k < 128; k++) acc += dot4(a[k], w[k]);
  proj_key[(b*3 + k3)*512 + h] = acc;
}

// ---------------- fused GRU cell: one thread per (b,h), 6 dot products ----------------
// x = concat(x1, x2) when x2 != nullptr (KX=1024), else x = x1 (KX=512)
__global__ __launch_bounds__(64) void k_gru(const float* __restrict__ x1, const float* __restrict__ x2,
    const float* __restrict__ h_in, const float* __restrict__ w_ih,
    const float* __restrict__ w_hh, const float* __restrict__ b_ih,
    const float* __restrict__ b_hh, float* __restrict__ h_out, int KX)
{
  int i = blockIdx.x*64 + threadIdx.x;    // 16384
  int b = i & 31, h = i >> 5;
  const float4* xv = (const float4*)(x1 + b*512);
  const float4* wr = (const float4*)(w_ih + (size_t)h*KX);
  const float4* wz = (const float4*)(w_ih + (size_t)(512+h)*KX);
  const float4* wn = (const float4*)(w_ih + (size_t)(1024+h)*KX);
  float ir = 0.f, iz = 0.f, inn = 0.f;
  #pragma unroll 4
  for (int k = 0; k < 128; k++) {
    float4 a = xv[k];
    ir  += dot4(a, wr[k]);
    iz  += dot4(a, wz[k]);
    inn += dot4(a, wn[k]);
  }
  if (x2) {
    const float4* x2v = (const float4*)(x2 + b*512);
    #pragma unroll 4
    for (int k = 0; k < 128; k++) {
      float4 a = x2v[k];
      ir  += dot4(a, wr[128+k]);
      iz  += dot4(a, wz[128+k]);
      inn += dot4(a, wn[128+k]);
    }
  }
  const float4* hv = (const float4*)(h_in + b*512);
  const float4* ur = (const float4*)(w_hh + (size_t)h*512);
  const float4* uz = (const float4*)(w_hh + (size_t)(512+h)*512);
  const float4* un = (const float4*)(w_hh + (size_t)(1024+h)*512);
  float hr = 0.f, hz = 0.f, hn = 0.f;
  #pragma unroll 4
  for (int k = 0; k < 128; k++) {
    float4 a = hv[k];
    hr += dot4(a, ur[k]);
    hz += dot4(a, uz[k]);
    hn += dot4(a, un[k]);
  }
  ir += b_ih[h]; iz += b_ih[512+h]; inn += b_ih[1024+h];
  hr += b_hh[h]; hz += b_hh[512+h]; hn += b_hh[1024+h];
  float r = 1.f/(1.f + expf(-(ir+hr)));
  float z = 1.f/(1.f + expf(-(iz+hz)));
  float n = tanhf(inn + r*hn);
  h_out[b*512+h] = (1.f - z)*n + z*h_in[b*512+h];
}

// ---------------- attention + context projection: one block per batch row ----------------
__global__ __launch_bounds__(256) void k_attn(const float* __restrict__ h1n, const float* __restrict__ proj_key,
    const float* __restrict__ attr_cat, const float* __restrict__ query_w, const float* __restrict__ energy_w,
    const float* __restrict__ ctx_w, const float* __restrict__ ctx_b, float* __restrict__ ctx_out)
{
  __shared__ float h1s[512];
  __shared__ float q[512];
  __shared__ float cv[512];
  __shared__ float red3[768];
  __shared__ float al[3];
  int b = blockIdx.x, tid = threadIdx.x;
  for (int h = tid; h < 512; h += 256) h1s[h] = h1n[b*512 + h];
  __syncthreads();
  const float4* xv = (const float4*)h1s;
  for (int h = tid; h < 512; h += 256) {
    const float4* w = (const float4*)(query_w + (size_t)h*512);
    float acc = 0.f;
    #pragma unroll 8
    for (int k = 0; k < 128; k++) acc += dot4(xv[k], w[k]);
    q[h] = acc;
  }
  __syncthreads();
  float s0 = 0.f, s1 = 0.f, s2 = 0.f;
  for (int h = tid; h < 512; h += 256) {
    float e = energy_w[h], qq = q[h];
    s0 += tanhf(qq + proj_key[(b*3+0)*512 + h]) * e;
    s1 += tanhf(qq + proj_key[(b*3+1)*512 + h]) * e;
    s2 += tanhf(qq + proj_key[(b*3+2)*512 + h]) * e;
  }
  red3[tid] = s0; red3[256+tid] = s1; red3[512+tid] = s2;
  __syncthreads();
  for (int st = 128; st > 0; st >>= 1) {
    if (tid < st) {
      red3[tid]     += red3[tid+st];
      red3[256+tid] += red3[256+tid+st];
      red3[512+tid] += red3[512+tid+st];
    }
    __syncthreads();
  }
  if (tid == 0) {
    float sc0 = red3[0], sc1 = red3[256], sc2 = red3[512];
    float mx = fmaxf(sc0, fmaxf(sc1, sc2));
    float e0 = expf(sc0-mx), e1 = expf(sc1-mx), e2 = expf(sc2-mx);
    float inv = 1.f/(e0+e1+e2);
    al[0] = e0*inv; al[1] = e1*inv; al[2] = e2*inv;
  }
  __syncthreads();
  for (int a = tid; a < 512; a += 256)
    cv[a] = al[0]*attr_cat[b*1536 + a] + al[1]*attr_cat[b*1536 + 512 + a] + al[2]*attr_cat[b*1536 + 1024 + a];
  __syncthreads();
  const float4* cvv = (const float4*)cv;
  for (int h = tid; h < 512; h += 256) {
    const float4* w1 = (const float4*)(ctx_w + (size_t)h*1024);
    const float4* w2 = w1 + 128;
    float acc = ctx_b[h];
    #pragma unroll 8
    for (int k = 0; k < 128; k++) { acc += dot4(xv[k], w1[k]); acc += dot4(cvv[k], w2[k]); }
    ctx_out[b*512 + h] = tanhf(acc);
  }
}

// ---------------- batched generator GEMM: logits[m=t*32+b][v] -> out[(b*T+t)*V + v] ----------------
// act: [640,512] row-major (ctx_all slots 1..20). Block: 32 cols x 8 m-groups, each thread 4 rows.
__global__ __launch_bounds__(256) void k_gen(const float* __restrict__ act, const float* __restrict__ gen_w,
    float* __restrict__ out)
{
  int nl = threadIdx.x & 31;
  int mg = threadIdx.x >> 5;            // 0..7
  int col = blockIdx.x*32 + nl;
  bool valid = col < VV;
  const float4* Bv = (const float4*)(gen_w + (size_t)(valid ? col : 0)*512);
  for (int mb = 0; mb < 640; mb += 32) {
    int m0 = mb + mg*4;
    const float4* A0 = (const float4*)(act + (size_t)m0*512);
    const float4* A1 = A0 + 128;
    const float4* A2 = A0 + 256;
    const float4* A3 = A0 + 384;
    float a0 = 0.f, a1 = 0.f, a2 = 0.f, a3 = 0.f;
    #pragma unroll 4
    for (int k = 0; k < 128; k++) {
      float4 bb = Bv[k];
      a0 += dot4(A0[k], bb);
      a1 += dot4(A1[k], bb);
      a2 += dot4(A2[k], bb);
      a3 += dot4(A3[k], bb);
    }
    if (valid) {
      int m;
      m = m0+0; out[(size_t)((m&31)*TT + (m>>5))*VV + col] = a0;
      m = m0+1; out[(size_t)((m&31)*TT + (m>>5))*VV + col] = a1;
      m = m0+2; out[(size_t)((m&31)*TT + (m>>5))*VV + col] = a2;
      m = m0+3; out[(size_t)((m&31)*TT + (m>>5))*VV + col] = a3;
    }
  }
}

// ---------------- in-place row-wise log_softmax over V=30000: one block per (b,t) row ----------------
__global__ __launch_bounds__(256) void k_logsm(float* __restrict__ out)
{
  __shared__ float red[256];
  int row = blockIdx.x, tid = threadIdx.x;
  float* p = out + (size_t)row*VV;
  float4* pv = (float4*)p;
  float m = -1e30f;
  for (int i = tid; i < VV/4; i += 256) {
    float4 v = pv[i];
    m = fmaxf(m, fmaxf(fmaxf(v.x, v.y), fmaxf(v.z, v.w)));
  }
  red[tid] = m; __syncthreads();
  for (int st = 128; st > 0; st >>= 1) { if (tid < st) red[tid] = fmaxf(red[tid], red[tid+st]); __syncthreads(); }
  m = red[0]; __syncthreads();
  float s = 0.f;
  for (int i = tid; i < VV/4; i += 256) {
    float4 v = pv[i];
    s += __expf(v.x-m) + __expf(v.y-m) + __expf(v.z-m) + __expf(v.w-m);
  }
  red[tid] = s; __syncthreads();
  for (int st = 128; st > 0; st >>= 1) { if (tid < st) red[tid] += red[tid+st]; __syncthreads(); }
  float lse = m + logf(red[0]);
  for (int i = tid; i < VV/4; i += 256) {
    float4 v = pv[i];
    v.x -= lse; v.y -= lse; v.z -= lse; v.w -= lse;
    pv[i] = v;
  }
}

extern "C" void kernel_launch(void* const* d_in, const int* in_sizes, int n_in,
                              void* d_out, int out_size, void* d_ws, size_t ws_size,
                              hipStream_t stream)
{
  const int*   user      = (const int*)d_in[0];
  const int*   product   = (const int*)d_in[1];
  const int*   rating    = (const int*)d_in[2];
  const int*   trg       = (const int*)d_in[3];
  // d_in[4] = trg_lengths (unused by reference)
  const float* embed     = (const float*)d_in[5];
  const float* user_w    = (const float*)d_in[6];
  const float* product_w = (const float*)d_in[7];
  const float* rating_w  = (const float*)d_in[8];
  const float* enc_w     = (const float*)d_in[9];
  const float* enc_b     = (const float*)d_in[10];
  const float* w_ih0     = (const float*)d_in[11];
  const float* w_hh0     = (const float*)d_in[12];
  const float* b_ih0     = (const float*)d_in[13];
  const float* b_hh0     = (const float*)d_in[14];
  const float* w_ih1     = (const float*)d_in[15];
  const float* w_hh1     = (const float*)d_in[16];
  const float* b_ih1     = (const float*)d_in[17];
  const float* b_hh1     = (const float*)d_in[18];
  const float* key_w     = (const float*)d_in[19];
  const float* query_w   = (const float*)d_in[20];
  const float* energy_w  = (const float*)d_in[21];
  const float* ctx_w     = (const float*)d_in[22];
  const float* ctx_b     = (const float*)d_in[23];
  const float* gen_w     = (const float*)d_in[24];
  float* out = (float*)d_out;

  // workspace layout (floats); total ~836K floats = 3.2 MB
  float* ws       = (float*)d_ws;
  float* attr_cat = ws;                  // 32*1536            = 49152
  float* xs       = attr_cat + 49152;    // 20*32*512          = 327680
  float* proj_key = xs + 327680;         // 32*3*512           = 49152
  float* h0buf    = proj_key + 49152;    // 2*32*512 ping-pong = 32768
  float* h1buf    = h0buf + 32768;       // 2*32*512           = 32768
  float* ctx_all  = h1buf + 32768;       // 21*32*512 (slot0=init, slot t+1 = ctxn of step t)

  k_prep<<<1472, 256, 0, stream>>>(user, product, rating, trg, embed, user_w, product_w, rating_w,
                                   attr_cat, xs);
  k_enc<<<128, 256, 0, stream>>>(attr_cat, enc_w, enc_b, h0buf, h1buf, ctx_all);
  k_key<<<192, 256, 0, stream>>>(attr_cat, key_w, proj_key);

  for (int t = 0; t < TT; t++) {
    const float* xt   = xs + t*BB*512;
    const float* ctxt = ctx_all + t*BB*512;
    float* h0_in  = h0buf + (t & 1)*BB*512;
    float* h0_out = h0buf + ((t+1) & 1)*BB*512;
    float* h1_in  = h1buf + (t & 1)*BB*512;
    float* h1_out = h1buf + ((t+1) & 1)*BB*512;
    k_gru<<<256, 64, 0, stream>>>(xt, ctxt, h0_in, w_ih0, w_hh0, b_ih0, b_hh0, h0_out, 1024);
    k_gru<<<256, 64, 0, stream>>>(h0_out, nullptr, h1_in, w_ih1, w_hh1, b_ih1, b_hh1, h1_out, 512);
    k_attn<<<32, 256, 0, stream>>>(h1_out, proj_key, attr_cat, query_w, energy_w, ctx_w, ctx_b,
                                   ctx_all + (t+1)*BB*512);
  }

  k_gen<<<938, 256, 0, stream>>>(ctx_all + BB*512, gen_w, out);
  k_logsm<<<640, 256, 0, stream>>>(out);
}

// Round 2
// 3800.333 us; speedup vs baseline: 1.7328x; 1.7328x over previous
//
#include <hip/hip_runtime.h>
#include <math.h>

#define BB 32
#define TT 20
#define VV 30000

typedef short short8 __attribute__((ext_vector_type(8)));
typedef unsigned short ushort8 __attribute__((ext_vector_type(8)));
typedef float floatx4 __attribute__((ext_vector_type(4)));

__device__ __forceinline__ float dot4(float4 a, float4 b) {
  return a.x*b.x + a.y*b.y + a.z*b.z + a.w*b.w;
}

__device__ __forceinline__ unsigned short f2bf(float f) {
  unsigned int u = __builtin_bit_cast(unsigned int, f);
  u = u + 0x7fffu + ((u >> 16) & 1u);   // round-to-nearest-even
  return (unsigned short)(u >> 16);
}

// ---------------- fp32 -> bf16 bulk convert (8 elems/thread) ----------------
__global__ __launch_bounds__(256) void k_cvt(const float* __restrict__ src,
                                             unsigned short* __restrict__ dst, int n8)
{
  int i = blockIdx.x*256 + threadIdx.x;
  if (i >= n8) return;
  const float4* s = ((const float4*)src) + (size_t)i*2;
  float4 a = s[0], b = s[1];
  ushort8 v;
  v[0]=f2bf(a.x); v[1]=f2bf(a.y); v[2]=f2bf(a.z); v[3]=f2bf(a.w);
  v[4]=f2bf(b.x); v[5]=f2bf(b.y); v[6]=f2bf(b.z); v[7]=f2bf(b.w);
  ((ushort8*)dst)[i] = v;
}

// ---------------- prep: attr_cat gather + teacher-forced input embeddings ----------------
__global__ __launch_bounds__(256) void k_prep(const int* __restrict__ user, const int* __restrict__ product,
    const int* __restrict__ rating, const int* __restrict__ trg,
    const float* __restrict__ embed, const float* __restrict__ user_w,
    const float* __restrict__ product_w, const float* __restrict__ rating_w,
    float* __restrict__ attr_cat, float* __restrict__ xs)
{
  int i = blockIdx.x*256 + threadIdx.x;
  if (i < BB*1536) {
    int b = i / 1536, j = i - b*1536;
    float v;
    if (j < 512)       v = user_w[(size_t)user[b]*512 + j];
    else if (j < 1024) v = product_w[(size_t)product[b]*512 + (j-512)];
    else               v = rating_w[(size_t)rating[b]*512 + (j-1024)];
    attr_cat[i] = v;
  }
  int i2 = i - BB*1536;
  if (i2 >= 0 && i2 < TT*BB*512) {
    int t = i2 >> 14;
    int r = i2 & 16383;
    int b = r >> 9, e = r & 511;
    int tok = (t == 0) ? 1 : trg[b*TT + (t-1)];
    xs[i2] = embed[(size_t)tok*512 + e];
  }
}

// ---------------- encoder init states ----------------
__global__ __launch_bounds__(256) void k_enc(const float* __restrict__ attr_cat, const float* __restrict__ enc_w,
    const float* __restrict__ enc_b, float* __restrict__ h0, float* __restrict__ h1, float* __restrict__ ctx0)
{
  int i = blockIdx.x*256 + threadIdx.x;
  int b = i & 31, j = i >> 5;
  const float4* a = (const float4*)(attr_cat + b*1536);
  const float4* w = (const float4*)(enc_w + (size_t)j*1536);
  float acc = 0.f;
  #pragma unroll 8
  for (int k = 0; k < 384; k++) acc += dot4(a[k], w[k]);
  acc += enc_b[j];
  float v = acc > 0.f ? acc : 0.01f*acc;
  if (j < 512) h0[b*512 + j] = v;
  else { h1[b*512 + (j-512)] = v; ctx0[b*512 + (j-512)] = v; }
}

// ---------------- proj_key ----------------
__global__ __launch_bounds__(256) void k_key(const float* __restrict__ attr_cat, const float* __restrict__ key_w,
    float* __restrict__ proj_key)
{
  int i = blockIdx.x*256 + threadIdx.x;
  int b = i & 31, j = i >> 5;
  int k3 = j >> 9, h = j & 511;
  const float4* a = (const float4*)(attr_cat + b*1536 + k3*512);
  const float4* w = (const float4*)(key_w + (size_t)h*512);
  float acc = 0.f;
  #pragma unroll 8
  for (int k = 0; k < 128; k++) acc += dot4(a[k], w[k]);
  proj_key[(b*3 + k3)*512 + h] = acc;
}

// ---------------- gx_all[m][g] = b_ih0[g] + xs[m,:] . w_ih0[g, 0:512] ----------------
__global__ __launch_bounds__(256) void k_gx(const float* __restrict__ xs, const float* __restrict__ w_ih0,
    const float* __restrict__ b_ih0, float* __restrict__ gx)
{
  int i = blockIdx.x*256 + threadIdx.x;     // 640*1536
  int m = i / 1536, g = i - m*1536;
  const float4* xv = (const float4*)(xs + (size_t)m*512);
  const float4* wv = (const float4*)(w_ih0 + (size_t)g*1024);
  float a = b_ih0[g];
  #pragma unroll 4
  for (int k = 0; k < 128; k++) a += dot4(xv[k], wv[k]);
  gx[i] = a;
}

// ---------------- GRU cell, 8-way K-split, one block per h (all 32 b) ----------------
// i-gates: x . wi[(g*512+h)*wi_stride + ks*64 ...]   (wi pre-offset for col slice)
// gx (if non-null): precomputed x-part incl. bias, [32][1536]
__global__ __launch_bounds__(256) void k_gru2(
    const float* __restrict__ x, const float* __restrict__ h_in,
    const float* __restrict__ wi, int wi_stride,
    const float* __restrict__ wh,
    const float* __restrict__ gx, const float* __restrict__ bi,
    const float* __restrict__ bh, float* __restrict__ h_out)
{
  int tid = threadIdx.x;
  int ks = tid & 7;
  int b  = tid >> 3;
  int h  = blockIdx.x;
  const float4* xv = (const float4*)(x + b*512 + ks*64);
  const float4* hv = (const float4*)(h_in + b*512 + ks*64);
  float acc[6];
  #pragma unroll
  for (int g = 0; g < 3; g++) {
    const float4* wiv = (const float4*)(wi + (size_t)(g*512 + h)*wi_stride + ks*64);
    const float4* whv = (const float4*)(wh + (size_t)(g*512 + h)*512 + ks*64);
    float ai = 0.f, ah = 0.f;
    #pragma unroll
    for (int k = 0; k < 16; k++) { ai += dot4(xv[k], wiv[k]); ah += dot4(hv[k], whv[k]); }
    acc[g] = ai; acc[3+g] = ah;
  }
  #pragma unroll
  for (int d = 1; d < 8; d <<= 1) {
    #pragma unroll
    for (int j = 0; j < 6; j++) acc[j] += __shfl_xor(acc[j], d);
  }
  if (ks == 0) {
    float ir = acc[0], iz = acc[1], inn = acc[2];
    float hr = acc[3], hz = acc[4], hn = acc[5];
    if (gx) { ir += gx[b*1536 + h]; iz += gx[b*1536 + 512 + h]; inn += gx[b*1536 + 1024 + h]; }
    else    { ir += bi[h]; iz += bi[512+h]; inn += bi[1024+h]; }
    hr += bh[h]; hz += bh[512+h]; hn += bh[1024+h];
    float r = 1.f/(1.f + expf(-(ir+hr)));
    float z = 1.f/(1.f + expf(-(iz+hz)));
    float n = tanhf(inn + r*hn);
    h_out[b*512+h] = (1.f - z)*n + z*h_in[b*512+h];
  }
}

// ---------------- q = h1n @ query_w.T, 8-way K-split ----------------
__global__ __launch_bounds__(256) void k_q(const float* __restrict__ h1n, const float* __restrict__ query_w,
    float* __restrict__ q)
{
  int tid = threadIdx.x; int ks = tid & 7; int b = tid >> 3; int h = blockIdx.x;
  const float4* xv = (const float4*)(h1n + b*512 + ks*64);
  const float4* wv = (const float4*)(query_w + (size_t)h*512 + ks*64);
  float a = 0.f;
  #pragma unroll
  for (int k = 0; k < 16; k++) a += dot4(xv[k], wv[k]);
  #pragma unroll
  for (int d = 1; d < 8; d <<= 1) a += __shfl_xor(a, d);
  if (ks == 0) q[b*512+h] = a;
}

// ---------------- scores + softmax + context, one block per b ----------------
__global__ __launch_bounds__(256) void k_attn_sc(const float* __restrict__ q, const float* __restrict__ proj_key,
    const float* __restrict__ attr_cat, const float* __restrict__ energy_w, float* __restrict__ context)
{
  __shared__ float red3[768];
  __shared__ float al[3];
  int b = blockIdx.x, tid = threadIdx.x;
  float s0 = 0.f, s1 = 0.f, s2 = 0.f;
  for (int h = tid; h < 512; h += 256) {
    float e = energy_w[h], qq = q[b*512 + h];
    s0 += tanhf(qq + proj_key[(b*3+0)*512 + h]) * e;
    s1 += tanhf(qq + proj_key[(b*3+1)*512 + h]) * e;
    s2 += tanhf(qq + proj_key[(b*3+2)*512 + h]) * e;
  }
  red3[tid] = s0; red3[256+tid] = s1; red3[512+tid] = s2;
  __syncthreads();
  for (int st = 128; st > 0; st >>= 1) {
    if (tid < st) {
      red3[tid]     += red3[tid+st];
      red3[256+tid] += red3[256+tid+st];
      red3[512+tid] += red3[512+tid+st];
    }
    __syncthreads();
  }
  if (tid == 0) {
    float sc0 = red3[0], sc1 = red3[256], sc2 = red3[512];
    float mx = fmaxf(sc0, fmaxf(sc1, sc2));
    float e0 = expf(sc0-mx), e1 = expf(sc1-mx), e2 = expf(sc2-mx);
    float inv = 1.f/(e0+e1+e2);
    al[0] = e0*inv; al[1] = e1*inv; al[2] = e2*inv;
  }
  __syncthreads();
  for (int a = tid; a < 512; a += 256)
    context[b*512 + a] = al[0]*attr_cat[b*1536 + a] + al[1]*attr_cat[b*1536 + 512 + a]
                       + al[2]*attr_cat[b*1536 + 1024 + a];
}

// ---------------- ctxn = tanh([h1n, context] @ ctx_w.T + ctx_b), 8-way K-split ----------------
__global__ __launch_bounds__(256) void k_ctx(const float* __restrict__ h1n, const float* __restrict__ context,
    const float* __restrict__ ctx_w, const float* __restrict__ ctx_b, float* __restrict__ out)
{
  int tid = threadIdx.x; int ks = tid & 7; int b = tid >> 3; int h = blockIdx.x;
  const float4* xv = (const float4*)(h1n + b*512 + ks*64);
  const float4* cv = (const float4*)(context + b*512 + ks*64);
  const float4* w1 = (const float4*)(ctx_w + (size_t)h*1024 + ks*64);
  const float4* w2 = (const float4*)(ctx_w + (size_t)h*1024 + 512 + ks*64);
  float a = 0.f;
  #pragma unroll
  for (int k = 0; k < 16; k++) { a += dot4(xv[k], w1[k]); a += dot4(cv[k], w2[k]); }
  #pragma unroll
  for (int d = 1; d < 8; d <<= 1) a += __shfl_xor(a, d);
  if (ks == 0) out[b*512+h] = tanhf(a + ctx_b[h]);
}

// ---------------- generator GEMM: bf16 MFMA, 128x128 tile, BK=64 ----------------
// A: act_bf [640][512] bf16 (m = t*32+b), B: genw_bf [30000][512] bf16 (B^T form)
// C[m][v] -> out[((m&31)*TT + (m>>5))*VV + v]
__global__ __launch_bounds__(256) void k_gen(const unsigned short* __restrict__ Abf,
    const unsigned short* __restrict__ Bbf, float* __restrict__ out)
{
  __shared__ unsigned short As[128*64];
  __shared__ unsigned short Bs[128*64];
  int tid = threadIdx.x;
  int ntile = blockIdx.x, mtile = blockIdx.y;
  int lane = tid & 63, wave = tid >> 6;
  int quad = lane >> 4, l15 = lane & 15;
  int wm = (wave >> 1) * 64, wn = (wave & 1) * 64;
  int m0 = mtile * 128, n0 = ntile * 128;
  floatx4 acc[4][4] = {};
  for (int kt = 0; kt < 8; kt++) {
    __syncthreads();
    #pragma unroll
    for (int c = 0; c < 4; c++) {
      int f = c*256 + tid;
      int row = f >> 3, k8 = (f & 7) * 8;
      ((short8*)As)[f] = *(const short8*)(Abf + (size_t)(m0 + row)*512 + kt*64 + k8);
      int vr = n0 + row; if (vr > VV-1) vr = VV-1;
      ((short8*)Bs)[f] = *(const short8*)(Bbf + (size_t)vr*512 + kt*64 + k8);
    }
    __syncthreads();
    #pragma unroll
    for (int ks = 0; ks < 2; ks++) {
      short8 af[4], bfr[4];
      #pragma unroll
      for (int i = 0; i < 4; i++)
        af[i] = *(const short8*)&As[(wm + i*16 + l15)*64 + ks*32 + quad*8];
      #pragma unroll
      for (int j = 0; j < 4; j++)
        bfr[j] = *(const short8*)&Bs[(wn + j*16 + l15)*64 + ks*32 + quad*8];
      #pragma unroll
      for (int i = 0; i < 4; i++)
        #pragma unroll
        for (int j = 0; j < 4; j++)
          acc[i][j] = __builtin_amdgcn_mfma_f32_16x16x32_bf16(af[i], bfr[j], acc[i][j], 0, 0, 0);
    }
  }
  #pragma unroll
  for (int i = 0; i < 4; i++) {
    int mbase = m0 + wm + i*16 + quad*4;
    #pragma unroll
    for (int j = 0; j < 4; j++) {
      int v = n0 + wn + j*16 + l15;
      if (v < VV) {
        #pragma unroll
        for (int r = 0; r < 4; r++) {
          int m = mbase + r;
          out[(size_t)((m & 31)*TT + (m >> 5))*VV + v] = acc[i][j][r];
        }
      }
    }
  }
}

// ---------------- in-place row-wise log_softmax over V=30000 ----------------
__global__ __launch_bounds__(256) void k_logsm(float* __restrict__ out)
{
  __shared__ float red[256];
  int row = blockIdx.x, tid = threadIdx.x;
  float* p = out + (size_t)row*VV;
  float4* pv = (float4*)p;
  float m = -1e30f;
  for (int i = tid; i < VV/4; i += 256) {
    float4 v = pv[i];
    m = fmaxf(m, fmaxf(fmaxf(v.x, v.y), fmaxf(v.z, v.w)));
  }
  red[tid] = m; __syncthreads();
  for (int st = 128; st > 0; st >>= 1) { if (tid < st) red[tid] = fmaxf(red[tid], red[tid+st]); __syncthreads(); }
  m = red[0]; __syncthreads();
  float s = 0.f;
  for (int i = tid; i < VV/4; i += 256) {
    float4 v = pv[i];
    s += __expf(v.x-m) + __expf(v.y-m) + __expf(v.z-m) + __expf(v.w-m);
  }
  red[tid] = s; __syncthreads();
  for (int st = 128; st > 0; st >>= 1) { if (tid < st) red[tid] += red[tid+st]; __syncthreads(); }
  float lse = m + logf(red[0]);
  for (int i = tid; i < VV/4; i += 256) {
    float4 v = pv[i];
    v.x -= lse; v.y -= lse; v.z -= lse; v.w -= lse;
    pv[i] = v;
  }
}

extern "C" void kernel_launch(void* const* d_in, const int* in_sizes, int n_in,
                              void* d_out, int out_size, void* d_ws, size_t ws_size,
                              hipStream_t stream)
{
  const int*   user      = (const int*)d_in[0];
  const int*   product   = (const int*)d_in[1];
  const int*   rating    = (const int*)d_in[2];
  const int*   trg       = (const int*)d_in[3];
  const float* embed     = (const float*)d_in[5];
  const float* user_w    = (const float*)d_in[6];
  const float* product_w = (const float*)d_in[7];
  const float* rating_w  = (const float*)d_in[8];
  const float* enc_w     = (const float*)d_in[9];
  const float* enc_b     = (const float*)d_in[10];
  const float* w_ih0     = (const float*)d_in[11];
  const float* w_hh0     = (const float*)d_in[12];
  const float* b_ih0     = (const float*)d_in[13];
  const float* b_hh0     = (const float*)d_in[14];
  const float* w_ih1     = (const float*)d_in[15];
  const float* w_hh1     = (const float*)d_in[16];
  const float* b_ih1     = (const float*)d_in[17];
  const float* b_hh1     = (const float*)d_in[18];
  const float* key_w     = (const float*)d_in[19];
  const float* query_w   = (const float*)d_in[20];
  const float* energy_w  = (const float*)d_in[21];
  const float* ctx_w     = (const float*)d_in[22];
  const float* ctx_b     = (const float*)d_in[23];
  const float* gen_w     = (const float*)d_in[24];
  float* out = (float*)d_out;

  // workspace layout
  float* ws       = (float*)d_ws;
  float* attr_cat = ws;                    // 49152
  float* xs       = attr_cat + 49152;      // 327680
  float* proj_key = xs + 327680;           // 49152
  float* h0buf    = proj_key + 49152;      // 32768
  float* h1buf    = h0buf + 32768;         // 32768
  float* ctx_all  = h1buf + 32768;         // 21*16384 = 344064
  float* gx_all   = ctx_all + 344064;      // 640*1536 = 983040
  float* qbuf     = gx_all + 983040;       // 16384
  float* context  = qbuf + 16384;          // 16384
  unsigned short* genw_bf = (unsigned short*)(context + 16384);  // 15,360,000 shorts
  unsigned short* act_bf  = genw_bf + 15360000;                  // 327,680 shorts

  k_cvt<<<7500, 256, 0, stream>>>(gen_w, genw_bf, 1920000);
  k_prep<<<1472, 256, 0, stream>>>(user, product, rating, trg, embed, user_w, product_w, rating_w,
                                   attr_cat, xs);
  k_enc<<<128, 256, 0, stream>>>(attr_cat, enc_w, enc_b, h0buf, h1buf, ctx_all);
  k_key<<<192, 256, 0, stream>>>(attr_cat, key_w, proj_key);
  k_gx<<<3840, 256, 0, stream>>>(xs, w_ih0, b_ih0, gx_all);

  for (int t = 0; t < TT; t++) {
    const float* ctxt = ctx_all + t*BB*512;
    float* h0_in  = h0buf + (t & 1)*BB*512;
    float* h0_out = h0buf + ((t+1) & 1)*BB*512;
    float* h1_in  = h1buf + (t & 1)*BB*512;
    float* h1_out = h1buf + ((t+1) & 1)*BB*512;
    k_gru2<<<512, 256, 0, stream>>>(ctxt, h0_in, w_ih0 + 512, 1024, w_hh0,
                                    gx_all + (size_t)t*BB*1536, nullptr, b_hh0, h0_out);
    k_gru2<<<512, 256, 0, stream>>>(h0_out, h1_in, w_ih1, 512, w_hh1,
                                    nullptr, b_ih1, b_hh1, h1_out);
    k_q<<<512, 256, 0, stream>>>(h1_out, query_w, qbuf);
    k_attn_sc<<<32, 256, 0, stream>>>(qbuf, proj_key, attr_cat, energy_w, context);
    k_ctx<<<512, 256, 0, stream>>>(h1_out, context, ctx_w, ctx_b, ctx_all + (t+1)*BB*512);
  }

  k_cvt<<<160, 256, 0, stream>>>(ctx_all + BB*512, act_bf, 40960);
  dim3 ggrid(235, 5);
  k_gen<<<ggrid, 256, 0, stream>>>(act_bf, genw_bf, out);
  k_logsm<<<640, 256, 0, stream>>>(out);
}